// Round 18
// baseline (106.572 us; speedup 1.0000x reference)
//
#include <hip/hip_runtime.h>
#include <stdint.h>

#define NUM_LAYERS 24
#define LN_EPS 1e-5f
#define N_ROWS (256 * 8192)
#define NUM_BLOCKS 2048   // 8192 waves x 256 rows/wave, straight-line

typedef __attribute__((ext_vector_type(4)))  uint32_t u32x4;   // MFMA A/B operand
typedef __attribute__((ext_vector_type(16))) float    f32x16;  // 32x32 MFMA acc
typedef __attribute__((ext_vector_type(2)))  float    f32x2;
typedef __attribute__((ext_vector_type(2)))  __fp16   h16x2;

// ---- f16 packing helpers ----
__device__ __forceinline__ uint32_t pk_f16_rtz(float lo, float hi) {
    h16x2 v = __builtin_amdgcn_cvt_pkrtz(lo, hi);   // v_cvt_pkrtz_f16_f32
    uint32_t u; __builtin_memcpy(&u, &v, 4);
    return u;
}
__device__ __forceinline__ uint32_t pk_f16_rne(float lo, float hi) {  // setup only
    __fp16 a = (__fp16)lo, b = (__fp16)hi;
    uint16_t ua, ub;
    __builtin_memcpy(&ua, &a, 2); __builtin_memcpy(&ub, &b, 2);
    return (uint32_t)ua | ((uint32_t)ub << 16);
}
__device__ __forceinline__ uint32_t pk_relu_f16(uint32_t d) {  // v_pk_max_f16
    h16x2 v; __builtin_memcpy(&v, &d, 4);
    h16x2 z = {(__fp16)0.0f, (__fp16)0.0f};
    v = __builtin_elementwise_max(v, z);
    uint32_t u; __builtin_memcpy(&u, &v, 4);
    return u;
}

__device__ __forceinline__ u32x4 make_frag(uint32_t d0, uint32_t d1,
                                           uint32_t d2, uint32_t d3) {
    u32x4 f; f.x = d0; f.y = d1; f.z = d2; f.w = d3;
    return f;
}

// ---- inline-asm MFMA blocks (VGPR form, single s_nop guard) ----
__device__ __forceinline__ void mfma_l1(f32x16& d0, f32x16& d1,
                                        const u32x4& a0, const u32x4& a1,
                                        const u32x4& b) {
    asm("s_nop 2\n\t"
        "v_mfma_f32_32x32x16_f16 %0, %2, %4, 0\n\t"
        "v_mfma_f32_32x32x16_f16 %1, %3, %4, 0"
        : "=&v"(d0), "=&v"(d1)
        : "v"(a0), "v"(a1), "v"(b));
}
// Layer 2: two interleaved 4-deep chains, C-init = cinit (b2 folded).
__device__ __forceinline__ void mfma_l2(f32x16& c0, f32x16& c1, const f32x16& cinit,
                                        const u32x4& w0, const u32x4& w1,
                                        const u32x4& w2, const u32x4& w3,
                                        const u32x4& h00, const u32x4& h01,
                                        const u32x4& h02, const u32x4& h03,
                                        const u32x4& h10, const u32x4& h11,
                                        const u32x4& h12, const u32x4& h13) {
    asm("s_nop 2\n\t"
        "v_mfma_f32_32x32x16_f16 %0, %3, %7, %2\n\t"
        "v_mfma_f32_32x32x16_f16 %1, %3, %11, %2\n\t"
        "v_mfma_f32_32x32x16_f16 %0, %4, %8, %0\n\t"
        "v_mfma_f32_32x32x16_f16 %1, %4, %12, %1\n\t"
        "v_mfma_f32_32x32x16_f16 %0, %5, %9, %0\n\t"
        "v_mfma_f32_32x32x16_f16 %1, %5, %13, %1\n\t"
        "v_mfma_f32_32x32x16_f16 %0, %6, %10, %0\n\t"
        "v_mfma_f32_32x32x16_f16 %1, %6, %14, %1"
        : "=&v"(c0), "=&v"(c1)
        : "v"(cinit), "v"(w0), "v"(w1), "v"(w2), "v"(w3),
          "v"(h00), "v"(h01), "v"(h02), "v"(h03),
          "v"(h10), "v"(h11), "v"(h12), "v"(h13));
}
// Layer 3: two interleaved 2-deep chains (K=32 over units), C = inline 0.
__device__ __forceinline__ void mfma_l3(f32x16& s0, f32x16& s1,
                                        const u32x4& a30, const u32x4& a31,
                                        const u32x4& b00, const u32x4& b01,
                                        const u32x4& b10, const u32x4& b11) {
    asm("s_nop 2\n\t"
        "v_mfma_f32_32x32x16_f16 %0, %2, %4, 0\n\t"
        "v_mfma_f32_32x32x16_f16 %1, %2, %6, 0\n\t"
        "v_mfma_f32_32x32x16_f16 %0, %3, %5, %0\n\t"
        "v_mfma_f32_32x32x16_f16 %1, %3, %7, %1"
        : "=&v"(s0), "=&v"(s1)
        : "v"(a30), "v"(a31), "v"(b00), "v"(b01), "v"(b10), "v"(b11));
}
__device__ __forceinline__ void mfma_fence2(f32x16& c0, f32x16& c1) {
    asm volatile("s_nop 7\n\ts_nop 7\n\ts_nop 7" : "+v"(c0), "+v"(c1));
}

// canonical hidden index k placed at layer1-output row-position p (sigma) —
// makes C1's C-layout register order equal the layer2 fragment K order.
__device__ __forceinline__ int sigma_k(int p) {
    int hh = (p >> 2) & 1;
    int base = (p & 31) - 4 * hh;            // {0-3,8-11,16-19,24-27}
    int r = (base & 3) + 4 * (base >> 3);    // [0,16)
    return 32 * (p >> 5) + 16 * (r >> 3) + 8 * hh + (r & 7);
}

__global__ __launch_bounds__(256, 3) void router_mfma(
    const float* __restrict__ x,
    const float* __restrict__ ln_w,
    const float* __restrict__ ln_b,
    const float* __restrict__ W1,
    const float* __restrict__ b1,
    const float* __restrict__ W2,
    const float* __restrict__ b2,
    const float* __restrict__ W3,
    const float* __restrict__ b3,
    float* __restrict__ out)
{
    // ---- block-cooperative weight tables in LDS ----
    __shared__ uint32_t s_a1[2 * 64 * 4];   // a1f[mt][lane] 4 dwords
    __shared__ uint32_t s_w2[4 * 64 * 4];   // w2f[kt][lane] 4 dwords
    __shared__ float    s_b2[8 * 64 * 2];   // b2 pair per (r2,lane) for c2init
    __shared__ float    s_ln[8 * NUM_LAYERS];

    const int t = threadIdx.x;

    if (t < 8 * NUM_LAYERS) {
        const int q = t & 7, lid = t >> 3;
        s_ln[q * NUM_LAYERS + lid] =
            (q < 4) ? ln_w[lid * 4 + q] : ln_b[lid * 4 + (q - 4)];
    }
    if (t < 128) {
        const int mt = t >> 6, ln = t & 63;
        const int n32l = ln & 31, hl = ln >> 5;
        uint32_t d0 = 0, d1 = 0, d2 = 0;
        if (!hl) {                       // A cols k>=8 are zero
            const int k = sigma_k(mt * 32 + n32l);
            d0 = pk_f16_rne(W1[k * 5 + 0], W1[k * 5 + 1]);
            d1 = pk_f16_rne(W1[k * 5 + 2], W1[k * 5 + 3]);
            d2 = pk_f16_rne(W1[k * 5 + 4], b1[k]);
        }
        uint32_t* p = &s_a1[(mt * 64 + ln) * 4];
        p[0] = d0; p[1] = d1; p[2] = d2; p[3] = 0;
    }
    {
        const int kt = t >> 6, ln = t & 63;
        const int n32l = ln & 31, hl = ln >> 5;
        const float* wp = W2 + n32l * 64 + kt * 16 + hl * 8;
        const float4 lo = *(const float4*)(wp);
        const float4 hi = *(const float4*)(wp + 4);
        uint32_t* p = &s_w2[(kt * 64 + ln) * 4];
        p[0] = pk_f16_rne(lo.x, lo.y);
        p[1] = pk_f16_rne(lo.z, lo.w);
        p[2] = pk_f16_rne(hi.x, hi.y);
        p[3] = pk_f16_rne(hi.z, hi.w);
    }
#pragma unroll
    for (int e = t; e < 512; e += 256) {
        const int r2 = e >> 6, ln = e & 63;
        const int hl = ln >> 5;
        const int n = ((2 * r2) & 3) + 8 * (r2 >> 1) + 4 * hl;
        s_b2[e * 2 + 0] = b2[n];
        s_b2[e * 2 + 1] = b2[n + 1];
    }
    __syncthreads();

    const int lane = t & 63;
    const int wid  = t >> 6;
    const int n32  = lane & 31;
    const int h    = lane >> 5;

    // ---- per-wave persistent fragments ----
    u32x4 a1f[2], w2f[4];
#pragma unroll
    for (int mt = 0; mt < 2; ++mt)
        a1f[mt] = *(const u32x4*)&s_a1[(mt * 64 + lane) * 4];
#pragma unroll
    for (int kt = 0; kt < 4; ++kt)
        w2f[kt] = *(const u32x4*)&s_w2[(kt * 64 + lane) * 4];

    f32x16 c2init;
#pragma unroll
    for (int r2 = 0; r2 < 8; ++r2) {
        const f32x2 bp = *(const f32x2*)&s_b2[(r2 * 64 + lane) * 2];
        c2init[2 * r2]     = bp.x;
        c2init[2 * r2 + 1] = bp.y;
    }

    // Layer-3 A-frags: W3 on output-row m==0 only (lanes n32==0), else 0.
    // For MFMA kt: A[0][k=8h+j] = W3[(j&3) + 16*kt + 8*(j>>2) + 4*h]
    // (matches packing c2 reg 8kt+j at B slot j on lane-half h).
    u32x4 a3f[2] = {make_frag(0, 0, 0, 0), make_frag(0, 0, 0, 0)};
    if (n32 == 0) {
#pragma unroll
        for (int kt = 0; kt < 2; ++kt) {
            uint32_t dw[4];
#pragma unroll
            for (int d = 0; d < 4; ++d) {
                const int j0 = 2 * d, j1 = 2 * d + 1;
                const int u0 = (j0 & 3) + 16 * kt + 8 * (j0 >> 2) + 4 * h;
                const int u1 = (j1 & 3) + 16 * kt + 8 * (j1 >> 2) + 4 * h;
                dw[d] = pk_f16_rne(W3[u0], W3[u1]);
            }
            a3f[kt] = make_frag(dw[0], dw[1], dw[2], dw[3]);
        }
    }
    const float b3v = b3[0];

    // ---- straight line: this wave owns 256 consecutive rows (4 groups) ----
    const int w = blockIdx.x * 4 + wid;            // 0..8191
    const size_t rowBase = (size_t)w * 256;

    // issue ALL x loads up front (8 independent VMEM ops)
    float4 cv[4];
    float  cl[4];
#pragma unroll
    for (int g = 0; g < 4; ++g) {
        const float* p = x + (rowBase + 64 * g + lane) * 5;
        cv[g] = *(const float4*)p;
        cl[g] = p[4];
    }

#pragma unroll
    for (int g = 0; g < 4; ++g) {
        const size_t gbase = rowBase + 64 * g;

        // ---- LayerNorm of row (gbase + lane) ----
        int lid = (int)(cl[g] * (float)NUM_LAYERS);
        lid = lid < 0 ? 0 : (lid > NUM_LAYERS - 1 ? NUM_LAYERS - 1 : lid);

        const float m  = (cv[g].x + cv[g].y + cv[g].z + cv[g].w) * 0.25f;
        const float d0 = cv[g].x - m, d1 = cv[g].y - m,
                    d2 = cv[g].z - m, d3 = cv[g].w - m;
        const float var = (d0 * d0 + d1 * d1 + d2 * d2 + d3 * d3) * 0.25f;
        const float r   = rsqrtf(var + LN_EPS);

        const float xn0 = fmaf(d0, r * s_ln[0 * 24 + lid], s_ln[4 * 24 + lid]);
        const float xn1 = fmaf(d1, r * s_ln[1 * 24 + lid], s_ln[5 * 24 + lid]);
        const float xn2 = fmaf(d2, r * s_ln[2 * 24 + lid], s_ln[6 * 24 + lid]);
        const float xn3 = fmaf(d3, r * s_ln[3 * 24 + lid], s_ln[7 * 24 + lid]);

        // packed normed features (+1.0 slot at q=5 for the b1 fold)
        const uint32_t e0 = pk_f16_rtz(xn0, xn1);
        const uint32_t e1 = pk_f16_rtz(xn2, xn3);
        const uint32_t e2 = pk_f16_rtz(cl[g], 1.0f);
        const uint32_t x0 = __shfl_xor((int)e0, 32, 64);
        const uint32_t x1 = __shfl_xor((int)e1, 32, 64);
        const uint32_t x2 = __shfl_xor((int)e2, 32, 64);

        const u32x4 bf_t0 = make_frag(e0, e1, e2, 0u);   // rows +0..31
        const u32x4 bf_t1 = make_frag(x0, x1, x2, 0u);   // rows +32..63

        // ---- layer 1, tile 0 ----
        u32x4 h1f0[4], h1f1[4];
        {
            f32x16 c1a, c1b;
            mfma_l1(c1a, c1b, a1f[0], a1f[1], bf_t0);
            mfma_fence2(c1a, c1b);
#pragma unroll
            for (int kt = 0; kt < 4; ++kt) {
                const f32x16& c1 = (kt < 2) ? c1a : c1b;
                const int roff = 8 * (kt & 1);
                uint32_t dw[4];
#pragma unroll
                for (int d = 0; d < 4; ++d)
                    dw[d] = pk_relu_f16(
                        pk_f16_rtz(c1[roff + 2 * d], c1[roff + 2 * d + 1]));
                h1f0[kt] = make_frag(dw[0], dw[1], dw[2], dw[3]);
            }
        }
        // ---- layer 1, tile 1 ----
        {
            f32x16 c1a, c1b;
            mfma_l1(c1a, c1b, a1f[0], a1f[1], bf_t1);
            mfma_fence2(c1a, c1b);
#pragma unroll
            for (int kt = 0; kt < 4; ++kt) {
                const f32x16& c1 = (kt < 2) ? c1a : c1b;
                const int roff = 8 * (kt & 1);
                uint32_t dw[4];
#pragma unroll
                for (int d = 0; d < 4; ++d)
                    dw[d] = pk_relu_f16(
                        pk_f16_rtz(c1[roff + 2 * d], c1[roff + 2 * d + 1]));
                h1f1[kt] = make_frag(dw[0], dw[1], dw[2], dw[3]);
            }
        }

        // ---- layer 2: two interleaved chains, C-init = b2 ----
        f32x16 c2_0, c2_1;
        mfma_l2(c2_0, c2_1, c2init,
                w2f[0], w2f[1], w2f[2], w2f[3],
                h1f0[0], h1f0[1], h1f0[2], h1f0[3],
                h1f1[0], h1f1[1], h1f1[2], h1f1[3]);
        mfma_fence2(c2_0, c2_1);

        // ---- layer 3 as MFMA: pack relu(c2) regs into B-frags ----
        // sb_t[kt] dword d = pk(relu(c2[8kt+2d]), relu(c2[8kt+2d+1]))
        u32x4 sb0[2], sb1[2];
#pragma unroll
        for (int kt = 0; kt < 2; ++kt) {
            uint32_t dwa[4], dwb[4];
#pragma unroll
            for (int d = 0; d < 4; ++d) {
                const int rr = 8 * kt + 2 * d;
                dwa[d] = pk_relu_f16(pk_f16_rtz(c2_0[rr], c2_0[rr + 1]));
                dwb[d] = pk_relu_f16(pk_f16_rtz(c2_1[rr], c2_1[rr + 1]));
            }
            sb0[kt] = make_frag(dwa[0], dwa[1], dwa[2], dwa[3]);
            sb1[kt] = make_frag(dwb[0], dwb[1], dwb[2], dwb[3]);
        }

        f32x16 s0, s1;
        mfma_l3(s0, s1, a3f[0], a3f[1], sb0[0], sb0[1], sb1[0], sb1[1]);
        mfma_fence2(s0, s1);

        // D row 0 lives on h==0 lanes, reg 0, col = data row n32.
        if (!h) {
            out[gbase + n32]      = s0[0] + b3v;
            out[gbase + 32 + n32] = s1[0] + b3v;
        }
    }
}

extern "C" void kernel_launch(void* const* d_in, const int* in_sizes, int n_in,
                              void* d_out, int out_size, void* d_ws, size_t ws_size,
                              hipStream_t stream) {
    const float* x    = (const float*)d_in[0];
    const float* ln_w = (const float*)d_in[1];
    const float* ln_b = (const float*)d_in[2];
    const float* W1   = (const float*)d_in[3];
    const float* b1   = (const float*)d_in[4];
    const float* W2   = (const float*)d_in[5];
    const float* b2   = (const float*)d_in[6];
    const float* W3   = (const float*)d_in[7];
    const float* b3   = (const float*)d_in[8];
    float* out = (float*)d_out;

    router_mfma<<<NUM_BLOCKS, 256, 0, stream>>>(x, ln_w, ln_b, W1, b1, W2, b2,
                                                W3, b3, out);
}